// Round 5
// baseline (83.143 us; speedup 1.0000x reference)
//
#include <hip/hip_runtime.h>
#include <hip/hip_bf16.h>

// SmoothLDDTLoss: b=2, n=4096
// inputs: pred_coords f32[2,4096,3], true_coords f32[2,4096,3],
//         is_dna i32[2,4096], is_rna i32[2,4096], coords_mask i32[2,4096]
// output: scalar f32 = 1 - mean_b(lddt_b)
//
// sigma(.5-d)+sigma(1-d)+sigma(2-d)+sigma(4-d) = t*Q'(t)/Q(t), t=e^{-d} (exact).
// Coords pre-scaled by log2(e) so t = exp2(-|dt_s - dp_s|) is a raw v_exp_f32.
// Symmetry: eps/mask/cutoff are symmetric in (i,j), so sum over j>i only; the
// implicit 2x cancels in s/c. Diagonal excluded by the j>i predicate.

#define NRES 4096
#define NBATCH 2
#define TI 8
#define JTILE 1024

// scaled cutoffs: 15*log2(e), 30*log2(e)
#define CUT15 21.6404256133f
#define CUT30 43.2808512267f

// Q coefficients: elementary symmetric polys of {e^0.5, e^1, e^2, e^4}
#define S1 66.35420923f
#define S2 678.60880385f
#define S3 2039.58217570f
#define S4 1808.04241445f
// Q'(t)/4 coefficients
#define QP1 16.58855231f
#define QP2 339.30440193f
#define QP3 1529.68663177f
#define QP4 1808.04241445f

#define LOG2E 1.44269504089f

__global__ void pack_kernel(const float* __restrict__ pred,
                            const float* __restrict__ truec,
                            const int* __restrict__ dna,
                            const int* __restrict__ rna,
                            const int* __restrict__ cm,
                            float4* __restrict__ tp,
                            float4* __restrict__ pp)
{
    int idx = blockIdx.x * 256 + threadIdx.x;
    if (idx >= NRES * NBATCH) return;
    float nuc = ((dna[idx] | rna[idx]) != 0) ? 1.0f : 0.0f;
    float cmf = (cm[idx] != 0) ? 1.0f : 0.0f;
    tp[idx] = make_float4(truec[3*idx+0]*LOG2E, truec[3*idx+1]*LOG2E, truec[3*idx+2]*LOG2E, nuc);
    pp[idx] = make_float4(pred[3*idx+0]*LOG2E,  pred[3*idx+1]*LOG2E,  pred[3*idx+2]*LOG2E,  cmf);
}

__launch_bounds__(256, 4)
__global__ void lddt_main(const float4* __restrict__ tp,
                          const float4* __restrict__ pp,
                          float* __restrict__ acc)  // [0..1] sums, [2..3] counts
{
    const int b     = blockIdx.z;
    const int jt    = blockIdx.y;
    const int i0    = blockIdx.x * TI;
    const int jbase = jt * JTILE;

    // tile entirely below the diagonal (all j <= i): covered by symmetry
    if (jbase + JTILE - 1 <= i0) return;

    const int base = b * NRES;
    const int tid  = threadIdx.x;
    const bool straddle = (i0 >> 10) == jt;   // strip rows live inside this j-tile

    float tix[TI], tiy[TI], tiz[TI];
    float pix[TI], piy[TI], piz[TI];
    float cHi[TI], cLo[TI], jminf[TI];
    #pragma unroll
    for (int r = 0; r < TI; ++r) {
        float4 t4 = tp[base + i0 + r];
        float4 p4 = pp[base + i0 + r];
        tix[r] = t4.x; tiy[r] = t4.y; tiz[r] = t4.z;
        pix[r] = p4.x; piy[r] = p4.y; piz[r] = p4.z;
        bool cmi  = (p4.w != 0.0f);
        bool nuci = (t4.w != 0.0f);
        cHi[r] = cmi ? (nuci ? CUT30 : CUT15) : -1.0f;
        cLo[r] = cmi ? CUT15 : -1.0f;
        jminf[r] = straddle ? (float)(i0 + r) + 0.5f : -1.0f;  // need j > i
    }

    float s = 0.0f, c = 0.0f;

    float4 t4 = tp[base + jbase + tid];
    float4 p4 = pp[base + jbase + tid];

    #pragma unroll 1
    for (int jtl = 0; jtl < JTILE / 256; ++jtl) {
        // prefetch next sub-tile (wrap stays inside this block's j-tile)
        const int jn = jbase + tid + (((jtl + 1) & 3) << 8);
        float4 t4n = tp[base + jn];
        float4 p4n = pp[base + jn];

        const float wj   = p4.w;               // cm_j as 1.0/0.0
        const bool  nucj = (t4.w != 0.0f);
        const float fj   = (float)(jbase + tid + (jtl << 8));

        #pragma unroll
        for (int r = 0; r < TI; ++r) {
            float dx = tix[r] - t4.x, dy = tiy[r] - t4.y, dz = tiz[r] - t4.z;
            float dt = __builtin_amdgcn_sqrtf(dx*dx + dy*dy + dz*dz);
            float ex = pix[r] - p4.x, ey = piy[r] - p4.y, ez = piz[r] - p4.z;
            float dp = __builtin_amdgcn_sqrtf(ex*ex + ey*ey + ez*ez);

            float cutoff = nucj ? cHi[r] : cLo[r];
            float mf = (fj > jminf[r]) ? wj : 0.0f;   // j > i (upper triangle)
            mf = (dt < cutoff) ? mf : 0.0f;

            float t = __builtin_amdgcn_exp2f(-fabsf(dt - dp));  // v_exp_f32, -abs mod
            float Q  = 1.0f + t*(S1 + t*(S2 + t*(S3 + t*S4)));
            float Qp = QP1 + t*(QP2 + t*(QP3 + t*QP4)); // Q'(t)/4
            float rq = __builtin_amdgcn_rcpf(Q);

            s += mf * ((t * Qp) * rq);
            c += mf;
        }

        t4 = t4n; p4 = p4n;
    }

    // wave (64-lane) reduction
    #pragma unroll
    for (int o = 32; o > 0; o >>= 1) {
        s += __shfl_down(s, o, 64);
        c += __shfl_down(c, o, 64);
    }

    __shared__ float red_s[4];
    __shared__ float red_c[4];
    const int wid  = tid >> 6;
    const int lane = tid & 63;
    if (lane == 0) { red_s[wid] = s; red_c[wid] = c; }
    __syncthreads();

    if (tid == 0) {
        float ts = red_s[0] + red_s[1] + red_s[2] + red_s[3];
        float tc = red_c[0] + red_c[1] + red_c[2] + red_c[3];
        atomicAdd(&acc[b], ts);
        atomicAdd(&acc[NBATCH + b], tc);
    }
}

__global__ void lddt_final(const float* __restrict__ acc, float* __restrict__ out)
{
    float l0 = acc[0] / fmaxf(acc[2], 1.0f);
    float l1 = acc[1] / fmaxf(acc[3], 1.0f);
    out[0] = 1.0f - 0.5f * (l0 + l1);
}

extern "C" void kernel_launch(void* const* d_in, const int* in_sizes, int n_in,
                              void* d_out, int out_size, void* d_ws, size_t ws_size,
                              hipStream_t stream) {
    const float* pred  = (const float*)d_in[0];
    const float* truec = (const float*)d_in[1];
    const int*   dna   = (const int*)d_in[2];
    const int*   rna   = (const int*)d_in[3];
    const int*   cmask = (const int*)d_in[4];
    float* out = (float*)d_out;

    char* ws = (char*)d_ws;
    float*  acc = (float*)ws;                         // 4 floats
    float4* tp  = (float4*)(ws + 1024);               // 2*4096*16 B
    float4* pp  = (float4*)(ws + 1024 + NBATCH*NRES*16);

    (void)hipMemsetAsync(acc, 0, 4 * sizeof(float), stream);

    pack_kernel<<<(NRES*NBATCH + 255)/256, 256, 0, stream>>>(pred, truec, dna, rna, cmask, tp, pp);

    dim3 grid(NRES / TI, NRES / JTILE, NBATCH);
    lddt_main<<<grid, 256, 0, stream>>>(tp, pp, acc);

    lddt_final<<<1, 1, 0, stream>>>(acc, out);
}

// Round 6
// 46.867 us; speedup vs baseline: 1.7740x; 1.7740x over previous
//
#include <hip/hip_runtime.h>
#include <hip/hip_bf16.h>

// SmoothLDDTLoss: b=2, n=4096
// inputs: pred_coords f32[2,4096,3], true_coords f32[2,4096,3],
//         is_dna i32[2,4096], is_rna i32[2,4096], coords_mask i32[2,4096]
// output: scalar f32 = 1 - mean_b(lddt_b)
//
// sigma(.5-d)+sigma(1-d)+sigma(2-d)+sigma(4-d) = t*Q'(t)/Q(t), t=e^{-d} (exact).
// Coords pre-scaled by log2(e) so t = exp2(-|dt_s-dp_s|) is a raw v_exp_f32.
// Symmetry via cyclic half-shell: for o=(j-i) mod n, summing o in [1,n/2]
// (weight 1/2 at o==n/2, which both endpoints visit) = half the full i!=j sum
// for BOTH eps-sum and count -> ratio unchanged. Uniform work per block.

#define NRES 4096
#define NBATCH 2
#define TI 8
#define NTILE 9            // o in [0, 2304) covers needed [1, 2048+TI-1]

// scaled cutoffs: 15*log2(e), 30*log2(e)
#define CUT15 21.6404256133f
#define CUT30 43.2808512267f

// Q coefficients: elementary symmetric polys of {e^0.5, e^1, e^2, e^4}
#define S1 66.35420923f
#define S2 678.60880385f
#define S3 2039.58217570f
#define S4 1808.04241445f
// Q'(t)/4 coefficients
#define QP1 16.58855231f
#define QP2 339.30440193f
#define QP3 1529.68663177f
#define QP4 1808.04241445f

#define LOG2E 1.44269504089f

__global__ void pack_kernel(const float* __restrict__ pred,
                            const float* __restrict__ truec,
                            const int* __restrict__ dna,
                            const int* __restrict__ rna,
                            const int* __restrict__ cm,
                            float4* __restrict__ tp,
                            float4* __restrict__ pp)
{
    int idx = blockIdx.x * 256 + threadIdx.x;
    if (idx >= NRES * NBATCH) return;
    float nuc = ((dna[idx] | rna[idx]) != 0) ? 1.0f : 0.0f;
    float cmf = (cm[idx] != 0) ? 1.0f : 0.0f;
    tp[idx] = make_float4(truec[3*idx+0]*LOG2E, truec[3*idx+1]*LOG2E, truec[3*idx+2]*LOG2E, nuc);
    pp[idx] = make_float4(pred[3*idx+0]*LOG2E,  pred[3*idx+1]*LOG2E,  pred[3*idx+2]*LOG2E,  cmf);
}

// MODE 0: clean interior tile; MODE 1: lower edge (need o-r>=1);
// MODE 2: upper edge (need o-r<=2048, half weight at exactly 2048)
#define PAIR_LOOP(MODE)                                                     \
    _Pragma("unroll")                                                       \
    for (int r = 0; r < TI; ++r) {                                          \
        float dx = tix[r] - t4.x, dy = tiy[r] - t4.y, dz = tiz[r] - t4.z;   \
        float dt = __builtin_amdgcn_sqrtf(dx*dx + dy*dy + dz*dz);           \
        float ex = pix[r] - p4.x, ey = piy[r] - p4.y, ez = piz[r] - p4.z;   \
        float dp = __builtin_amdgcn_sqrtf(ex*ex + ey*ey + ez*ez);           \
        float cutoff = nucj ? cHi[r] : cLo[r];                              \
        float mf = (dt < cutoff) ? wj : 0.0f;                               \
        if (MODE == 1) mf = (o >= r + 1) ? mf : 0.0f;                       \
        if (MODE == 2) { int d = o - r;                                     \
            mf = (d <= 2048) ? mf : 0.0f;                                   \
            mf = (d == 2048) ? 0.5f * mf : mf; }                            \
        float t = __builtin_amdgcn_exp2f(-fabsf(dt - dp));                  \
        float Q  = 1.0f + t*(S1 + t*(S2 + t*(S3 + t*S4)));                  \
        float Qp = QP1 + t*(QP2 + t*(QP3 + t*QP4));                         \
        float rq = __builtin_amdgcn_rcpf(Q);                                \
        s += mf * ((t * Qp) * rq);                                          \
        c += mf;                                                            \
    }

__launch_bounds__(256, 4)
__global__ void lddt_main(const float4* __restrict__ tp,
                          const float4* __restrict__ pp,
                          float* __restrict__ acc)  // [0..1] sums, [2..3] counts
{
    const int b    = blockIdx.y;
    const int i0   = blockIdx.x * TI;
    const int base = b * NRES;
    const int tid  = threadIdx.x;

    float tix[TI], tiy[TI], tiz[TI];
    float pix[TI], piy[TI], piz[TI];
    float cHi[TI], cLo[TI];
    #pragma unroll
    for (int r = 0; r < TI; ++r) {
        float4 t4 = tp[base + i0 + r];
        float4 p4 = pp[base + i0 + r];
        tix[r] = t4.x; tiy[r] = t4.y; tiz[r] = t4.z;
        pix[r] = p4.x; piy[r] = p4.y; piz[r] = p4.z;
        bool cmi  = (p4.w != 0.0f);
        bool nuci = (t4.w != 0.0f);
        cHi[r] = cmi ? (nuci ? CUT30 : CUT15) : -1.0f;
        cLo[r] = cmi ? CUT15 : -1.0f;
    }

    float s = 0.0f, c = 0.0f;

    float4 t4 = tp[base + ((i0 + tid) & (NRES - 1))];
    float4 p4 = pp[base + ((i0 + tid) & (NRES - 1))];

    #pragma unroll 1
    for (int tl = 0; tl < NTILE; ++tl) {
        // prefetch next tile (last iter re-fetches tile 0; always in-bounds)
        const int on = (tl == NTILE - 1) ? tid : (tl + 1) * 256 + tid;
        const int jn = (i0 + on) & (NRES - 1);
        float4 t4n = tp[base + jn];
        float4 p4n = pp[base + jn];

        const float wj   = p4.w;               // cm_j as 1.0/0.0
        const bool  nucj = (t4.w != 0.0f);
        const int   o    = tl * 256 + tid;     // cyclic offset j-i

        if (tl == 0)            { PAIR_LOOP(1) }
        else if (tl == NTILE-1) { PAIR_LOOP(2) }
        else                    { PAIR_LOOP(0) }

        t4 = t4n; p4 = p4n;
    }

    // wave (64-lane) reduction
    #pragma unroll
    for (int off = 32; off > 0; off >>= 1) {
        s += __shfl_down(s, off, 64);
        c += __shfl_down(c, off, 64);
    }

    __shared__ float red_s[4];
    __shared__ float red_c[4];
    const int wid  = tid >> 6;
    const int lane = tid & 63;
    if (lane == 0) { red_s[wid] = s; red_c[wid] = c; }
    __syncthreads();

    if (tid == 0) {
        float ts = red_s[0] + red_s[1] + red_s[2] + red_s[3];
        float tc = red_c[0] + red_c[1] + red_c[2] + red_c[3];
        atomicAdd(&acc[b], ts);
        atomicAdd(&acc[NBATCH + b], tc);
    }
}

__global__ void lddt_final(const float* __restrict__ acc, float* __restrict__ out)
{
    float l0 = acc[0] / fmaxf(acc[2], 0.5f);
    float l1 = acc[1] / fmaxf(acc[3], 0.5f);
    out[0] = 1.0f - 0.5f * (l0 + l1);
}

extern "C" void kernel_launch(void* const* d_in, const int* in_sizes, int n_in,
                              void* d_out, int out_size, void* d_ws, size_t ws_size,
                              hipStream_t stream) {
    const float* pred  = (const float*)d_in[0];
    const float* truec = (const float*)d_in[1];
    const int*   dna   = (const int*)d_in[2];
    const int*   rna   = (const int*)d_in[3];
    const int*   cmask = (const int*)d_in[4];
    float* out = (float*)d_out;

    char* ws = (char*)d_ws;
    float*  acc = (float*)ws;                         // 4 floats
    float4* tp  = (float4*)(ws + 1024);               // 2*4096*16 B
    float4* pp  = (float4*)(ws + 1024 + NBATCH*NRES*16);

    (void)hipMemsetAsync(acc, 0, 4 * sizeof(float), stream);

    pack_kernel<<<(NRES*NBATCH + 255)/256, 256, 0, stream>>>(pred, truec, dna, rna, cmask, tp, pp);

    dim3 grid(NRES / TI, NBATCH);
    lddt_main<<<grid, 256, 0, stream>>>(tp, pp, acc);

    lddt_final<<<1, 1, 0, stream>>>(acc, out);
}